// Round 8
// baseline (99.068 us; speedup 1.0000x reference)
//
#include <hip/hip_runtime.h>
#include <cstdint>
#include <cstddef>

#define BB 8
#define CC 128
#define HH 96
#define WW 320
#define HW (HH*WW)        // 30720
#define NSEL 32
#define NSELH 16
#define K4CH 8            // chunks per plane in K4
#define GRID1 2048
#define STEPS 15          // 7864320 float4 / (2048*256)

typedef float f32x4 __attribute__((ext_vector_type(4)));

__device__ __forceinline__ float sigmoidf_(float x) {
  return __builtin_amdgcn_rcpf(1.0f + __expf(-x));
}

__device__ __forceinline__ float wred(float v) {
  #pragma unroll
  for (int m = 32; m >= 1; m >>= 1) v += __shfl_xor(v, m, 64);
  return v;
}

// K1: DENSE-FRONT grid-stride copy x->out + per-wave-per-step partial sums.
// At any instant the whole grid sweeps one contiguous 8 MB window (fill-style)
// instead of 2048 scattered chunks -> DRAM row locality. A wave's 64 float4
// never straddle a plane (7680 % 64 == 0), so per-step shfl-reduce is exact.
__global__ __launch_bounds__(256) void k_copy_reduce(
    const float* __restrict__ x, float* __restrict__ out,
    float* __restrict__ wpart) {
  int t = threadIdx.x;
  int blk = blockIdx.x;
  int wv = t >> 6;
  const f32x4* __restrict__ xi = (const f32x4*)x;
  f32x4* __restrict__ oi = (f32x4*)out;
  #pragma unroll 1
  for (int s = 0; s < STEPS; ++s) {
    int g = (s << 19) + blk*256 + t;      // float4 index, 2^19 = GRID1*256
    f32x4 v = xi[g];
    oi[g] = v;
    unsigned ip = (unsigned)g % 7680u;    // float4 index within plane
    int h = (int)(ip / 80u);              // row (WW/4 = 80)
    float d = 0.1f + (float)h * (0.9f/95.0f);
    float s0 = sigmoidf_(v.x), s1 = sigmoidf_(v.y);
    float s2 = sigmoidf_(v.z), s3 = sigmoidf_(v.w);
    float ts = (s0+s1)+(s2+s3);
    float qs = (s0*s0+s1*s1)+(s2*s2+s3*s3);
    float tw = wred(ts);
    float aw = wred(ts * d);
    float qw = wred(qs);
    if ((t & 63) == 0) {
      int m = (s << 13) + (blk << 2) + wv;   // (s*GRID1 + blk)*4 + wv
      wpart[m*3+0] = tw;
      wpart[m*3+1] = aw;
      wpart[m*3+2] = qw;
    }
  }
}

// K1b: per-plane reduction of the 120 wave-partials (fixed order, f64).
__global__ __launch_bounds__(128) void k_plane(
    const float* __restrict__ wpart, double* __restrict__ planesums) {
  int p = blockIdx.x;      // 0..1023 = b*CC + c
  int j = threadIdx.x;
  double t0=0.0, t1=0.0, t2=0.0;
  if (j < 120) {
    int g0 = p*7680 + j*64;              // float4 index of wave-slot start
    int s  = g0 >> 19;
    int r  = g0 & 524287;
    int m  = (s << 13) + ((r >> 8) << 2) + ((r & 255) >> 6);
    t0 = (double)wpart[m*3+0];
    t1 = (double)wpart[m*3+1];
    t2 = (double)wpart[m*3+2];
  }
  __shared__ double sh[3][128];
  sh[0][j]=t0; sh[1][j]=t1; sh[2][j]=t2;
  __syncthreads();
  for (int ofs=64; ofs>0; ofs>>=1) {
    if (j < ofs) {
      sh[0][j]+=sh[0][j+ofs];
      sh[1][j]+=sh[1][j+ofs];
      sh[2][j]+=sh[2][j+ofs];
    }
    __syncthreads();
  }
  if (j==0) {
    planesums[p*3+0]=sh[0][0];
    planesums[p*3+1]=sh[1][0];
    planesums[p*3+2]=sh[2][0];
  }
}

// K2: fused select (block 0) + runs (blocks 1..20).
__global__ __launch_bounds__(128) void k_select_runs(
    const double* __restrict__ planesums, const int* __restrict__ mask,
    int* __restrict__ idx, uint8_t* __restrict__ kk) {
  int t = threadIdx.x;
  if (blockIdx.x == 0) {
    int c = t;
    double T=0.0, A=0.0, Q=0.0;
    for (int b=0;b<BB;b++) {
      int p = b*CC + c;
      T += planesums[p*3+0];
      A += planesums[p*3+1];
      Q += planesums[p*3+2];
    }
    double sn = sqrt(Q); if (sn < 1e-6) sn = 1e-6;
    double c1 = A / sn;
    double c2 = (T - A) / sn;
    __shared__ double s1[CC], s2[CC];
    s1[c]=c1; s2[c]=c2;
    __syncthreads();
    int r1=0, r2=0;
    for (int j=0;j<CC;j++) {
      r1 += (s1[j] > c1) || (s1[j]==c1 && j<c);
      r2 += (s2[j] > c2) || (s2[j]==c2 && j<c);
    }
    if (r1 < NSELH) idx[r1] = c;
    if (r2 < NSELH) idx[NSELH + r2] = c;
  } else {
    int colid = (blockIdx.x - 1)*128 + t;   // 20*128 = 2560 = BB*WW
    int b = colid / WW;
    int w = colid - b*WW;
    const int* __restrict__ mcol = mask + (size_t)b*HW + w;
    unsigned long long lo=0ull, hi=0ull;
    #pragma unroll
    for (int h=0; h<64; ++h) lo |= (unsigned long long)(mcol[h*WW]!=0) << h;
    #pragma unroll
    for (int h=64; h<95; ++h) hi |= (unsigned long long)(mcol[h*WW]!=0) << (h-64);
    uint8_t* __restrict__ kcol = kk + (size_t)b*HW + w;
    #pragma unroll
    for (int h=0; h<96; ++h) {
      unsigned long long s;
      if (h == 0)      s = lo;
      else if (h < 64) s = (lo >> h) | (hi << (64-h));
      else             s = hi >> (h-64);
      int run = __builtin_ctzll(~s | (1ull<<33));
      kcol[h*WW] = (uint8_t)(run > 32 ? 32 : run);
    }
  }
}

// K4: per-(b,selc,chunk) partial max |prop-sel|. Grid BB*NSEL*K4CH = 2048.
__global__ __launch_bounds__(256) void k_maxdiff(
    const float* __restrict__ x, const int* __restrict__ idx,
    const uint8_t* __restrict__ kk, float* __restrict__ pmax) {
  int chunk = blockIdx.x & (K4CH-1);
  int bc32 = blockIdx.x >> 3;       // b*32 + c
  int b = bc32 >> 5;
  int c = bc32 & 31;
  int ic = idx[c];
  const float* __restrict__ base = x + ((size_t)b*CC + ic)*HW;
  const uint8_t* __restrict__ kb = kk + (size_t)b*HW;
  float mx = 0.0f;
  int lo = chunk * (HW/4/K4CH), hiend = lo + (HW/4/K4CH);
  for (int j = lo + threadIdx.x; j < hiend; j += 256) {
    f32x4 sel = ((const f32x4*)base)[j];
    uchar4 kv  = ((const uchar4*)kb)[j];
    int h = j / (WW/4);
    int w4 = (j - h*(WW/4))*4;
    float p0 = base[(h+(int)kv.x)*WW + w4+0];
    float p1 = base[(h+(int)kv.y)*WW + w4+1];
    float p2 = base[(h+(int)kv.z)*WW + w4+2];
    float p3 = base[(h+(int)kv.w)*WW + w4+3];
    mx = fmaxf(mx, fmaxf(fmaxf(fabsf(p0-sel.x), fabsf(p1-sel.y)),
                         fmaxf(fabsf(p2-sel.z), fabsf(p3-sel.w))));
  }
  __shared__ float sh[256];
  sh[threadIdx.x]=mx; __syncthreads();
  for (int ofs=128; ofs>0; ofs>>=1) {
    if ((int)threadIdx.x<ofs) sh[threadIdx.x]=fmaxf(sh[threadIdx.x], sh[threadIdx.x+ofs]);
    __syncthreads();
  }
  if (threadIdx.x==0) pmax[blockIdx.x] = sh[0];
}

// K5: finalize mclip from chunk maxes, then
// w = max_c clip(|prop-sel|/mclip_c,0,1); refined = w*prop + (1-w)*sel.
__global__ __launch_bounds__(WW) void k_refine(
    const float* __restrict__ x, const int* __restrict__ idx,
    const uint8_t* __restrict__ kk, const float* __restrict__ pmax,
    float* __restrict__ out) {
  int bh = blockIdx.x;
  int b = bh / HH, h = bh - b*HH;
  int w = threadIdx.x;
  __shared__ int sidx[NSEL];
  __shared__ float smc[NSEL];
  if (threadIdx.x < NSEL) {
    int c = threadIdx.x;
    sidx[c] = idx[c];
    float m = 0.0f;
    #pragma unroll
    for (int ch=0; ch<K4CH; ch++) m = fmaxf(m, pmax[(b*NSEL + c)*K4CH + ch]);
    m *= 0.3f;
    if (m == 0.0f) m = 1.0f;
    smc[c] = m;
  }
  __syncthreads();
  int r = h + (int)kk[(size_t)bh*WW + w];
  float sel[NSEL], prop[NSEL];
  float wmax = 0.0f;
  #pragma unroll
  for (int c=0;c<NSEL;c++) {
    const float* __restrict__ base = x + ((size_t)b*CC + sidx[c])*HW;
    sel[c]  = base[h*WW + w];
    prop[c] = base[r*WW + w];
    float v = fabsf(prop[c]-sel[c]) / smc[c];
    wmax = fmaxf(wmax, fminf(v, 1.0f));
  }
  #pragma unroll
  for (int c=0;c<NSEL;c++) {
    float rf = wmax*prop[c] + (1.0f - wmax)*sel[c];
    out[((size_t)b*CC + sidx[c])*HW + h*WW + w] = rf;
  }
}

extern "C" void kernel_launch(void* const* d_in, const int* in_sizes, int n_in,
                              void* d_out, int out_size, void* d_ws, size_t ws_size,
                              hipStream_t stream) {
  const float* x   = (const float*)d_in[0];
  const int* mask  = (const int*)d_in[1];
  float* out       = (float*)d_out;

  char* ws = (char*)d_ws;
  float*  wpart     = (float*)(ws);                        // 122880*3*4 = 1474560 B
  double* planesums = (double*)(ws + 1474560);             // 1024*3*8 = 24576 B
  int*    idx       = (int*)(ws + 1474560 + 24576);        // 128 B
  float*  pmax      = (float*)(ws + 1474560 + 24576 + 128);// 8192 B
  uint8_t* kk       = (uint8_t*)(ws + 1474560 + 24576 + 128 + 8192); // 245760 B

  k_copy_reduce<<<GRID1, 256, 0, stream>>>(x, out, wpart);
  k_plane<<<BB*CC, 128, 0, stream>>>(wpart, planesums);
  k_select_runs<<<21, 128, 0, stream>>>(planesums, mask, idx, kk);
  k_maxdiff<<<BB*NSEL*K4CH, 256, 0, stream>>>(x, idx, kk, pmax);
  k_refine<<<BB*HH, WW, 0, stream>>>(x, idx, kk, pmax, out);
}